// Round 4
// baseline (3221.106 us; speedup 1.0000x reference)
//
#include <hip/hip_runtime.h>
#include <math.h>

#define B_SZ 4096
#define D_SZ 1024
#define H_SZ 1024
#define T_SZ 50

typedef _Float16 f16;
typedef __attribute__((ext_vector_type(8))) _Float16 f16x8;
typedef __attribute__((ext_vector_type(4))) _Float16 f16x4;
typedef __attribute__((ext_vector_type(2))) _Float16 f16x2;
typedef __attribute__((ext_vector_type(4))) float f32x4;
typedef __attribute__((ext_vector_type(4))) float f4;

__device__ __forceinline__ float fast_sigmoid(float x) {
    return 1.0f / (1.0f + __expf(-x));
}
__device__ __forceinline__ float fast_tanh(float x) {
    return 1.0f - 2.0f / (__expf(2.0f * x) + 1.0f);
}

// async global->LDS, 16 bytes per lane
__device__ __forceinline__ void gl_lds16(const void* g, void* l) {
    __builtin_amdgcn_global_load_lds(
        (const __attribute__((address_space(1))) unsigned int*)g,
        (__attribute__((address_space(3))) unsigned int*)l, 16, 0, 0);
}

#define LGKM0() do { asm volatile("s_waitcnt lgkmcnt(0)" ::: "memory"); __builtin_amdgcn_sched_barrier(0); } while (0)

// ---------------------------------------------------------------------------
// fp32 -> fp16 conversion (4 elems/thread; n divisible by 4)
__global__ __launch_bounds__(256) void conv_kernel(
        const float* __restrict__ s, f16* __restrict__ d, int n) {
    int i = (blockIdx.x * 256 + threadIdx.x) * 4;
    if (i < n) {
        f4 v = *(const f4*)&s[i];
        f16x4 o = {(f16)v[0], (f16)v[1], (f16)v[2], (f16)v[3]};
        *(f16x4*)&d[i] = o;
    }
}

// ---------------------------------------------------------------------------
// teach (B,T,2) f32 -> tT (T,B,2) f16: coalesced per-step epilogue reads.
__global__ __launch_bounds__(256) void ttrans_kernel(
        const float* __restrict__ teach, f16* __restrict__ tT) {
    int idx = blockIdx.x * 256 + threadIdx.x;  // t*B + b
    if (idx >= T_SZ * B_SZ) return;
    int t = idx >> 12, b = idx & 4095;
    float v0 = teach[b * (T_SZ * 2) + t * 2 + 0];
    float v1 = teach[b * (T_SZ * 2) + t * 2 + 1];
    f16x2 o = {(f16)v0, (f16)v1};
    *(f16x2*)&tT[(size_t)idx * 2] = o;
}

// ---------------------------------------------------------------------------
// Prepack w_hh (3H,H) f32 into per-(jblock, kt32) tiles [192 rows][32 cols]
// f16, with the LDS slot swizzle (slot ^= (row>>1)&3 on 8-elem slots) baked
// in, so step-kernel B staging is perfectly linear gl_lds.
__global__ __launch_bounds__(256) void prepack_kernel(
        const float* __restrict__ w, f16* __restrict__ wpk) {
    const int idx = blockIdx.x * 256 + threadIdx.x;  // 0..767 (row,slot)
    const int kt = blockIdx.y, jb = blockIdx.z;
    const int row = idx >> 2, s = idx & 3;           // row 0..191
    const int g = row >> 6, jj = row & 63;
    const int col = (kt << 5) + ((s ^ ((row >> 1) & 3)) << 3);
    const float* src =
        w + ((size_t)(g << 10) + (jb << 6) + jj) * H_SZ + col;
    f4 v0 = *(const f4*)src;
    f4 v1 = *(const f4*)(src + 4);
    f16x8 o = {(f16)v0[0], (f16)v0[1], (f16)v0[2], (f16)v0[3],
               (f16)v1[0], (f16)v1[1], (f16)v1[2], (f16)v1[3]};
    *(f16x8*)&wpk[((size_t)jb * 32 + kt) * 6144 + idx * 8] = o;
}

// ---------------------------------------------------------------------------
// h0 = tanh(ev @ w_init^T + b_init) via fp16 MFMA.
__global__ __launch_bounds__(256, 2) void h0_kernel(
        const f16* __restrict__ ev, const f16* __restrict__ wi,
        const float* __restrict__ b_init, f16* __restrict__ hh) {
    __shared__ __align__(16) f16 lds[6144];  // A 128x32 @0, B 64x32 @4096
    const int tid = threadIdx.x;
    const int lane = tid & 63, wave = tid >> 6;
    const int b0 = blockIdx.y * 128, j0 = blockIdx.x * 64;
    const int wm = wave >> 1, wn = wave & 1;
    const int lrow = lane & 15, quad = lane >> 4;

    const f16* gsrc[3];
    int lbase[3];
    {
        const int row16 = lane >> 2, part = lane & 3;
#pragma unroll
        for (int i = 0; i < 3; ++i) {
            int c = wave + 4 * i;
            if (c < 8) {
                gsrc[i] = ev + (size_t)(b0 + c * 16 + row16) * D_SZ + part * 8;
                lbase[i] = c * 512;
            } else {
                int cc = c - 8;
                gsrc[i] = wi + (size_t)(j0 + cc * 16 + row16) * D_SZ + part * 8;
                lbase[i] = 4096 + cc * 512;
            }
        }
    }

    int offA[4], offB[2];
#pragma unroll
    for (int mi = 0; mi < 4; ++mi)
        offA[mi] = (wm * 64 + mi * 16 + lrow) * 32 + quad * 8;
#pragma unroll
    for (int ni = 0; ni < 2; ++ni)
        offB[ni] = 4096 + (wn * 32 + ni * 16 + lrow) * 32 + quad * 8;

    f32x4 acc[4][2] = {};

    for (int k0 = 0; k0 < D_SZ; k0 += 32) {
        __syncthreads();
#pragma unroll
        for (int i = 0; i < 3; ++i)
            gl_lds16(gsrc[i] + k0, &lds[lbase[i]] + lane * 8);
        __syncthreads();
        f16x8 aa[4], bb[2];
#pragma unroll
        for (int mi = 0; mi < 4; ++mi) aa[mi] = *(const f16x8*)&lds[offA[mi]];
#pragma unroll
        for (int ni = 0; ni < 2; ++ni) bb[ni] = *(const f16x8*)&lds[offB[ni]];
#pragma unroll
        for (int mi = 0; mi < 4; ++mi)
#pragma unroll
            for (int ni = 0; ni < 2; ++ni)
                acc[mi][ni] = __builtin_amdgcn_mfma_f32_16x16x32_f16(
                    aa[mi], bb[ni], acc[mi][ni], 0, 0, 0);
    }

#pragma unroll
    for (int ni = 0; ni < 2; ++ni) {
        const int j = j0 + wn * 32 + ni * 16 + lrow;
        const float bj = b_init[j];
#pragma unroll
        for (int mi = 0; mi < 4; ++mi)
#pragma unroll
            for (int reg = 0; reg < 4; ++reg) {
                const int b = b0 + wm * 64 + mi * 16 + quad * 4 + reg;
                hh[(size_t)b * H_SZ + j] = (f16)tanhf(acc[mi][ni][reg] + bj);
            }
    }
}

// ---------------------------------------------------------------------------
// Persistent GRU: ALL 50 steps in one cooperative dispatch.
// Grid 256 x 512 = 1 block/CU (LDS 140 KB). Same GEMM structure as v4:
// BM=256 x BN=192 x BK=32, 5 LDS buffers, prefetch depth 4, counted vmcnt,
// ONE s_barrier per K-tile. Between steps: per-by-group barrier (16 blocks;
// the 16 by-groups are fully independent across all 50 steps), with
// agent-scope release(wbl2)/acquire(inv) fences for cross-XCD visibility.
// Step t-1's delta partials reduced 1/16-per-block at top of step t.
// Epilogue j-constants (w_ih/b_ih/b_hh/w_out) hoisted out of the t-loop.
__global__ __launch_bounds__(512, 1) void steps_kernel(
        f16* hA, f16* hB, const f16* __restrict__ wpk,
        const float* __restrict__ b_hh, const float* __restrict__ w_ih,
        const float* __restrict__ b_ih, const float* __restrict__ w_out,
        const f16* __restrict__ tT, float* out, float* pA, float* pB,
        int* barc) {
    constexpr int TILE_E = 14336;  // f16/buffer: A 256x32=8192 + B 192x32=6144
    __shared__ __align__(16) f16 lds[5 * TILE_E];  // 140 KB
    const int tid = threadIdx.x;
    const int lane = tid & 63, wave = tid >> 6;
    const int wm = wave >> 1, wn = wave & 1;
    // XCD-aware swizzle: id%8 = XCD; a by-group's 16 blocks span 2 XCDs.
    const int id = blockIdx.x;
    const int xcd = id & 7, slot = id >> 3;
    const int bx = (xcd & 1) * 8 + (slot & 7);
    const int by = (xcd >> 1) * 4 + (slot >> 3);
    const int b0 = by * 256, j0 = bx * 64;
    const int lrow = lane & 15, quad = lane >> 4;

    // ---- loop-invariant staging geometry ----
    const f16* gb = wpk + (size_t)bx * (32 * 6144);
    const int srow = tid >> 2;
    const int scol = ((tid & 3) ^ ((tid >> 3) & 3)) * 8;  // inverse swizzle
    const size_t aoff = (size_t)(b0 + srow) * H_SZ + scol;

    // ---- fragment read offsets (swizzled; 2-way bank aliasing = free) ----
    const int swz = (quad ^ ((lrow >> 1) & 3)) * 8;
    int offA[4], offB[6];
#pragma unroll
    for (int mi = 0; mi < 4; ++mi)
        offA[mi] = (wm * 64 + mi * 16 + lrow) * 32 + swz;
#pragma unroll
    for (int f = 0; f < 6; ++f)
        offB[f] = 8192 + ((f >> 1) * 64 + wn * 32 + (f & 1) * 16 + lrow) * 32 + swz;

    // ---- hoisted epilogue j-constants ----
    float ewr0[2], ewr1[2], ewz0[2], ewz1[2], ewn0[2], ewn1[2];
    float ebr[2], ebz[2], ebn[2], ehbn[2], ewo0[2], ewo1[2];
#pragma unroll
    for (int ni = 0; ni < 2; ++ni) {
        const int j = j0 + wn * 32 + ni * 16 + lrow;
        ewr0[ni] = w_ih[(0 * H_SZ + j) * 2 + 0];
        ewr1[ni] = w_ih[(0 * H_SZ + j) * 2 + 1];
        ewz0[ni] = w_ih[(1 * H_SZ + j) * 2 + 0];
        ewz1[ni] = w_ih[(1 * H_SZ + j) * 2 + 1];
        ewn0[ni] = w_ih[(2 * H_SZ + j) * 2 + 0];
        ewn1[ni] = w_ih[(2 * H_SZ + j) * 2 + 1];
        ebr[ni] = b_ih[0 * H_SZ + j] + b_hh[0 * H_SZ + j];
        ebz[ni] = b_ih[1 * H_SZ + j] + b_hh[1 * H_SZ + j];
        ebn[ni] = b_ih[2 * H_SZ + j];
        ehbn[ni] = b_hh[2 * H_SZ + j];
        ewo0[ni] = w_out[j];
        ewo1[ni] = w_out[H_SZ + j];
    }

    for (int t = 0; t < T_SZ; ++t) {
        const f16* hc = (t & 1) ? hB : hA;
        f16* hn = (t & 1) ? hA : hB;
        const float* partP = (t & 1) ? pA : pB;
        float* partC = (t & 1) ? pB : pA;

        // ---- reduce previous step's delta partials (1/16 per block) ----
        if (t > 0 && tid < 32) {
            const int b = b0 + bx * 16 + (tid >> 1), cc = tid & 1;
            float s = 0.f;
#pragma unroll
            for (int x = 0; x < 16; ++x) s += partP[x * 8192 + b * 2 + cc];
            out[b * (T_SZ * 2) + (t - 1) * 2 + cc] = s;
        }

        const f16* ga[4];
#pragma unroll
        for (int i = 0; i < 4; ++i) ga[i] = hc + aoff + (size_t)i * 64 * H_SZ;

        auto issueT = [&](int kt, int sb) {
            if (tid < 256) {
#pragma unroll
                for (int i = 0; i < 4; ++i)
                    gl_lds16(ga[i] + kt * 32, &lds[sb + i * 2048 + tid * 8]);
#pragma unroll
                for (int i = 0; i < 3; ++i)
                    gl_lds16(gb + kt * 6144 + i * 2048 + tid * 8,
                             &lds[sb + 8192 + i * 2048 + tid * 8]);
            }
        };

        f32x4 acc[3][4][2] = {};

        // ---- prologue: 4 tiles in flight ----
        issueT(0, 0);
        issueT(1, TILE_E);
        issueT(2, 2 * TILE_E);
        issueT(3, 3 * TILE_E);

        int rb = 0, sb = 4 * TILE_E;
        for (int tt = 0; tt < 32; ++tt) {
            if (tt < 29)       asm volatile("s_waitcnt vmcnt(21)" ::: "memory");
            else if (tt == 29) asm volatile("s_waitcnt vmcnt(14)" ::: "memory");
            else if (tt == 30) asm volatile("s_waitcnt vmcnt(7)" ::: "memory");
            else               asm volatile("s_waitcnt vmcnt(0)" ::: "memory");
            __builtin_amdgcn_s_barrier();
            asm volatile("" ::: "memory");
            f16x8 aa[4], bv[6];
#pragma unroll
            for (int mi = 0; mi < 4; ++mi)
                aa[mi] = *(const f16x8*)&lds[rb + offA[mi]];
#pragma unroll
            for (int f = 0; f < 6; ++f)
                bv[f] = *(const f16x8*)&lds[rb + offB[f]];
            if (tt < 28) issueT(tt + 4, sb);
            LGKM0();
            __builtin_amdgcn_s_setprio(1);
#pragma unroll
            for (int f = 0; f < 6; ++f) {
                const int g = f >> 1, ni = f & 1;
#pragma unroll
                for (int mi = 0; mi < 4; ++mi)
                    acc[g][mi][ni] = __builtin_amdgcn_mfma_f32_16x16x32_f16(
                        aa[mi], bv[f], acc[g][mi][ni], 0, 0, 0);
            }
            __builtin_amdgcn_s_setprio(0);
            rb += TILE_E; if (rb == 5 * TILE_E) rb = 0;
            sb += TILE_E; if (sb == 5 * TILE_E) sb = 0;
        }

        // -------- fused epilogue: gates, h_next, delta partials --------
        float p0[4][4], p1[4][4];
#pragma unroll
        for (int mi = 0; mi < 4; ++mi)
#pragma unroll
            for (int reg = 0; reg < 4; ++reg) {
                const int b = b0 + wm * 64 + mi * 16 + quad * 4 + reg;
                if (t > 0) {
                    f16x2 tv = *(const f16x2*)&tT[((size_t)(t - 1) * B_SZ + b) * 2];
                    p0[mi][reg] = (float)tv[0];
                    p1[mi][reg] = (float)tv[1];
                } else {
                    p0[mi][reg] = 0.f;
                    p1[mi][reg] = 0.f;
                }
            }

        float s0[4][4] = {}, s1[4][4] = {};
#pragma unroll
        for (int ni = 0; ni < 2; ++ni) {
            const int j = j0 + wn * 32 + ni * 16 + lrow;
#pragma unroll
            for (int mi = 0; mi < 4; ++mi) {
#pragma unroll
                for (int reg = 0; reg < 4; ++reg) {
                    const int b = b0 + wm * 64 + mi * 16 + quad * 4 + reg;
                    const float hr = acc[0][mi][ni][reg];
                    const float hz = acc[1][mi][ni][reg];
                    const float hn_ = acc[2][mi][ni][reg] + ehbn[ni];
                    const float xr = ewr0[ni] * p0[mi][reg] + ewr1[ni] * p1[mi][reg] + ebr[ni];
                    const float xz = ewz0[ni] * p0[mi][reg] + ewz1[ni] * p1[mi][reg] + ebz[ni];
                    const float xn = ewn0[ni] * p0[mi][reg] + ewn1[ni] * p1[mi][reg] + ebn[ni];
                    const float r = fast_sigmoid(xr + hr);
                    const float z = fast_sigmoid(xz + hz);
                    const float n = fast_tanh(xn + r * hn_);
                    const size_t idx = (size_t)b * H_SZ + j;
                    const float hold = (float)hc[idx];
                    const float hnew = (1.0f - z) * n + z * hold;
                    hn[idx] = (f16)hnew;
                    s0[mi][reg] += hnew * ewo0[ni];
                    s1[mi][reg] += hnew * ewo1[ni];
                }
            }
        }

        // per-wave lrow-reduction, then cross-wn merge via LDS, store partials
        float ra[4][4], rc[4][4];
#pragma unroll
        for (int mi = 0; mi < 4; ++mi)
#pragma unroll
            for (int reg = 0; reg < 4; ++reg) {
                float a = s0[mi][reg], c = s1[mi][reg];
#pragma unroll
                for (int m = 1; m < 16; m <<= 1) {
                    a += __shfl_xor(a, m);
                    c += __shfl_xor(c, m);
                }
                ra[mi][reg] = a;
                rc[mi][reg] = c;
            }
        float* red = (float*)lds;  // 2 KB scratch; K-loop LDS fully consumed
        __syncthreads();           // all waves done with buffer-0 reads
        if (wn == 1 && lrow == 0) {
#pragma unroll
            for (int mi = 0; mi < 4; ++mi)
#pragma unroll
                for (int reg = 0; reg < 4; ++reg) {
                    const int key = wm * 64 + mi * 16 + quad * 4 + reg;
                    red[key * 2 + 0] = ra[mi][reg];
                    red[key * 2 + 1] = rc[mi][reg];
                }
        }
        __syncthreads();
        if (wn == 0 && lrow == 0) {
#pragma unroll
            for (int mi = 0; mi < 4; ++mi)
#pragma unroll
                for (int reg = 0; reg < 4; ++reg) {
                    const int key = wm * 64 + mi * 16 + quad * 4 + reg;
                    const int b = b0 + key;
                    partC[bx * 8192 + b * 2 + 0] = ra[mi][reg] + red[key * 2 + 0];
                    partC[bx * 8192 + b * 2 + 1] = rc[mi][reg] + red[key * 2 + 1];
                }
        }

        // ---- inter-step per-by-group barrier (16 blocks) ----
        if (t < T_SZ - 1) {
            __syncthreads();  // drains all this block's stores (vmcnt 0)
            if (tid == 0) {
                __builtin_amdgcn_fence(__ATOMIC_RELEASE, "agent");  // wbl2
                __hip_atomic_fetch_add(&barc[by], 1, __ATOMIC_RELAXED,
                                       __HIP_MEMORY_SCOPE_AGENT);
                const int target = 16 * (t + 1);
                while (__hip_atomic_load(&barc[by], __ATOMIC_RELAXED,
                                         __HIP_MEMORY_SCOPE_AGENT) < target)
                    __builtin_amdgcn_s_sleep(2);
                __builtin_amdgcn_fence(__ATOMIC_ACQUIRE, "agent");  // inv
            }
            __syncthreads();
        }
    }
}

// ---------------------------------------------------------------------------
// pred_deltas += b_out (t<49 already reduced into out); t=49 reduced here
// from the last partial buffer; pred_pos = cumsum.
__global__ __launch_bounds__(256) void final_kernel(
        float* __restrict__ out, float* __restrict__ pos,
        const float* __restrict__ b_out, const float* __restrict__ partLast) {
    int idx = blockIdx.x * 256 + threadIdx.x;  // b*2 + c
    if (idx >= B_SZ * 2) return;
    int b = idx >> 1, c = idx & 1;
    float bc = b_out[c];
    float acc = 0.0f;
    for (int t = 0; t < T_SZ - 1; ++t) {
        float d = out[b * (T_SZ * 2) + t * 2 + c] + bc;
        out[b * (T_SZ * 2) + t * 2 + c] = d;
        acc += d;
        pos[b * (T_SZ * 2) + t * 2 + c] = acc;
    }
    float s = 0.f;
#pragma unroll
    for (int x = 0; x < 16; ++x) s += partLast[x * 8192 + b * 2 + c];
    float d = s + bc;
    out[b * (T_SZ * 2) + (T_SZ - 1) * 2 + c] = d;
    acc += d;
    pos[b * (T_SZ * 2) + (T_SZ - 1) * 2 + c] = acc;
}

// ---------------------------------------------------------------------------
extern "C" void kernel_launch(void* const* d_in, const int* in_sizes, int n_in,
                              void* d_out, int out_size, void* d_ws, size_t ws_size,
                              hipStream_t stream) {
    const float* ev     = (const float*)d_in[0];
    const float* teach  = (const float*)d_in[1];
    const float* w_init = (const float*)d_in[2];
    const float* b_init = (const float*)d_in[3];
    const float* w_ih   = (const float*)d_in[4];
    const float* w_hh   = (const float*)d_in[5];
    const float* b_ih   = (const float*)d_in[6];
    const float* b_hh   = (const float*)d_in[7];
    const float* w_out  = (const float*)d_in[8];
    const float* b_out  = (const float*)d_in[9];

    float* out = (float*)d_out;                  // pred_deltas (B,T,2)
    float* pos = out + (size_t)B_SZ * T_SZ * 2;  // pred_pos    (B,T,2)

    // ws layout (f16 units): hA (4M), hB (4M), wpk (3M), winit (1M) = 24 MB.
    // ev_f16 aliases hB. After h0, winit region is dead and reused for:
    //   tT (f16, 409600 elems) @ winit+0
    //   pA (f32, 131072) @ winit+417792 (f16 units), pB after it,
    //   barc (int, 16) @ winit+942080 (ends 942112 < 1048576).
    f16* ws = (f16*)d_ws;
    f16* hA    = ws;
    f16* hB    = hA + (size_t)B_SZ * H_SZ;
    f16* wpk   = hB + (size_t)B_SZ * H_SZ;
    f16* winit = wpk + (size_t)3 * H_SZ * H_SZ;
    f16* evf   = hB;  // alias
    f16* tT    = winit;
    float* pA  = (float*)(winit + 417792);
    float* pB  = pA + 131072;
    int* barc  = (int*)(winit + 942080);

    conv_kernel<<<(H_SZ * D_SZ) / 1024, 256, 0, stream>>>(w_init, winit, H_SZ * D_SZ);
    conv_kernel<<<(B_SZ * D_SZ) / 1024, 256, 0, stream>>>(ev, evf, B_SZ * D_SZ);
    prepack_kernel<<<dim3(3, 32, 16), 256, 0, stream>>>(w_hh, wpk);

    dim3 g0(H_SZ / 64, B_SZ / 128);  // (16, 32)
    h0_kernel<<<g0, 256, 0, stream>>>(evf, winit, b_init, hA);

    // winit consumed; build tT / zero barc in its place
    ttrans_kernel<<<(T_SZ * B_SZ + 255) / 256, 256, 0, stream>>>(teach, tT);
    hipMemsetAsync(barc, 0, 16 * sizeof(int), stream);

    const float* bhh_p = b_hh; const float* wih_p = w_ih;
    const float* bih_p = b_ih; const float* wout_p = w_out;
    void* args[] = {&hA, &hB, &wpk, &bhh_p, &wih_p, &bih_p, &wout_p,
                    &tT, &out, &pA, &pB, &barc};
    hipLaunchCooperativeKernel((const void*)steps_kernel, dim3(256), dim3(512),
                               args, 0, stream);

    // t=49 is odd -> its partials are in pB
    final_kernel<<<(B_SZ * 2 + 255) / 256, 256, 0, stream>>>(out, pos, b_out, pB);
}

// Round 6
// 1887.586 us; speedup vs baseline: 1.7065x; 1.7065x over previous
//
#include <hip/hip_runtime.h>
#include <math.h>

#define B_SZ 4096
#define D_SZ 1024
#define H_SZ 1024
#define T_SZ 50

typedef _Float16 f16;
typedef __attribute__((ext_vector_type(8))) _Float16 f16x8;
typedef __attribute__((ext_vector_type(4))) _Float16 f16x4;
typedef __attribute__((ext_vector_type(2))) _Float16 f16x2;
typedef __attribute__((ext_vector_type(4))) float f32x4;
typedef __attribute__((ext_vector_type(4))) float f4;

__device__ __forceinline__ float fast_sigmoid(float x) {
    return 1.0f / (1.0f + __expf(-x));
}
__device__ __forceinline__ float fast_tanh(float x) {
    return 1.0f - 2.0f / (__expf(2.0f * x) + 1.0f);
}

// async global->LDS, 16 bytes per lane
__device__ __forceinline__ void gl_lds16(const void* g, void* l) {
    __builtin_amdgcn_global_load_lds(
        (const __attribute__((address_space(1))) unsigned int*)g,
        (__attribute__((address_space(3))) unsigned int*)l, 16, 0, 0);
}

#define LGKM0() do { asm volatile("s_waitcnt lgkmcnt(0)" ::: "memory"); __builtin_amdgcn_sched_barrier(0); } while (0)

// ---------------------------------------------------------------------------
// fp32 -> fp16 conversion (4 elems/thread; n divisible by 4)
__global__ __launch_bounds__(256) void conv_kernel(
        const float* __restrict__ s, f16* __restrict__ d, int n) {
    int i = (blockIdx.x * 256 + threadIdx.x) * 4;
    if (i < n) {
        f4 v = *(const f4*)&s[i];
        f16x4 o = {(f16)v[0], (f16)v[1], (f16)v[2], (f16)v[3]};
        *(f16x4*)&d[i] = o;
    }
}

// ---------------------------------------------------------------------------
// teach (B,T,2) f32 -> tT (T,B,2) f16: coalesced per-step epilogue reads.
__global__ __launch_bounds__(256) void ttrans_kernel(
        const float* __restrict__ teach, f16* __restrict__ tT) {
    int idx = blockIdx.x * 256 + threadIdx.x;  // t*B + b
    if (idx >= T_SZ * B_SZ) return;
    int t = idx >> 12, b = idx & 4095;
    float v0 = teach[b * (T_SZ * 2) + t * 2 + 0];
    float v1 = teach[b * (T_SZ * 2) + t * 2 + 1];
    f16x2 o = {(f16)v0, (f16)v1};
    *(f16x2*)&tT[(size_t)idx * 2] = o;
}

// ---------------------------------------------------------------------------
// Prepack w_hh (3H,H) f32 into per-(jblock, kt32) tiles [192 rows][32 cols]
// f16, with the LDS slot swizzle (slot ^= (row>>1)&3 on 8-elem slots) baked
// in, so step-kernel B staging is perfectly linear gl_lds.
__global__ __launch_bounds__(256) void prepack_kernel(
        const float* __restrict__ w, f16* __restrict__ wpk) {
    const int idx = blockIdx.x * 256 + threadIdx.x;  // 0..767 (row,slot)
    const int kt = blockIdx.y, jb = blockIdx.z;
    const int row = idx >> 2, s = idx & 3;           // row 0..191
    const int g = row >> 6, jj = row & 63;
    const int col = (kt << 5) + ((s ^ ((row >> 1) & 3)) << 3);
    const float* src =
        w + ((size_t)(g << 10) + (jb << 6) + jj) * H_SZ + col;
    f4 v0 = *(const f4*)src;
    f4 v1 = *(const f4*)(src + 4);
    f16x8 o = {(f16)v0[0], (f16)v0[1], (f16)v0[2], (f16)v0[3],
               (f16)v1[0], (f16)v1[1], (f16)v1[2], (f16)v1[3]};
    *(f16x8*)&wpk[((size_t)jb * 32 + kt) * 6144 + idx * 8] = o;
}

// ---------------------------------------------------------------------------
// h0 = tanh(ev @ w_init^T + b_init) via fp16 MFMA.
__global__ __launch_bounds__(256, 2) void h0_kernel(
        const f16* __restrict__ ev, const f16* __restrict__ wi,
        const float* __restrict__ b_init, f16* __restrict__ hh) {
    __shared__ __align__(16) f16 lds[6144];  // A 128x32 @0, B 64x32 @4096
    const int tid = threadIdx.x;
    const int lane = tid & 63, wave = tid >> 6;
    const int b0 = blockIdx.y * 128, j0 = blockIdx.x * 64;
    const int wm = wave >> 1, wn = wave & 1;
    const int lrow = lane & 15, quad = lane >> 4;

    const f16* gsrc[3];
    int lbase[3];
    {
        const int row16 = lane >> 2, part = lane & 3;
#pragma unroll
        for (int i = 0; i < 3; ++i) {
            int c = wave + 4 * i;
            if (c < 8) {
                gsrc[i] = ev + (size_t)(b0 + c * 16 + row16) * D_SZ + part * 8;
                lbase[i] = c * 512;
            } else {
                int cc = c - 8;
                gsrc[i] = wi + (size_t)(j0 + cc * 16 + row16) * D_SZ + part * 8;
                lbase[i] = 4096 + cc * 512;
            }
        }
    }

    int offA[4], offB[2];
#pragma unroll
    for (int mi = 0; mi < 4; ++mi)
        offA[mi] = (wm * 64 + mi * 16 + lrow) * 32 + quad * 8;
#pragma unroll
    for (int ni = 0; ni < 2; ++ni)
        offB[ni] = 4096 + (wn * 32 + ni * 16 + lrow) * 32 + quad * 8;

    f32x4 acc[4][2] = {};

    for (int k0 = 0; k0 < D_SZ; k0 += 32) {
        __syncthreads();
#pragma unroll
        for (int i = 0; i < 3; ++i)
            gl_lds16(gsrc[i] + k0, &lds[lbase[i]] + lane * 8);
        __syncthreads();
        f16x8 aa[4], bb[2];
#pragma unroll
        for (int mi = 0; mi < 4; ++mi) aa[mi] = *(const f16x8*)&lds[offA[mi]];
#pragma unroll
        for (int ni = 0; ni < 2; ++ni) bb[ni] = *(const f16x8*)&lds[offB[ni]];
#pragma unroll
        for (int mi = 0; mi < 4; ++mi)
#pragma unroll
            for (int ni = 0; ni < 2; ++ni)
                acc[mi][ni] = __builtin_amdgcn_mfma_f32_16x16x32_f16(
                    aa[mi], bb[ni], acc[mi][ni], 0, 0, 0);
    }

#pragma unroll
    for (int ni = 0; ni < 2; ++ni) {
        const int j = j0 + wn * 32 + ni * 16 + lrow;
        const float bj = b_init[j];
#pragma unroll
        for (int mi = 0; mi < 4; ++mi)
#pragma unroll
            for (int reg = 0; reg < 4; ++reg) {
                const int b = b0 + wm * 64 + mi * 16 + quad * 4 + reg;
                hh[(size_t)b * H_SZ + j] = (f16)tanhf(acc[mi][ni][reg] + bj);
            }
    }
}

// ---------------------------------------------------------------------------
// One GRU step v5: deep-pipelined fp16 MFMA GEMM, BM=128 x BN=192 x BK=32,
// 256 threads = 4 waves (2M x 2N); grid 512 = 2 blocks/CU (LDS 80 KB:
// 4 buffers x 20 KB). Two co-resident blocks hide each other's vmcnt/barrier
// stalls (the R3 structure had 1 block/CU and nothing to overlap with).
// Prefetch depth 3, counted s_waitcnt vmcnt(10), ONE s_barrier per K-tile;
// vmcnt reaches 0 only on the last tile. LDS slot-swizzle as R3 (2-way free).
// Delta partials: per-bx non-atomic buffers (ping-pong), reduced at the top
// of the NEXT step's dispatch (1/16 per block: 8 rows x 2 comps = 16 lanes).
__global__ __launch_bounds__(256, 2) void step_kernel(
        const f16* __restrict__ hh, const f16* __restrict__ wpk,
        const float* __restrict__ b_hh, const float* __restrict__ w_ih,
        const float* __restrict__ b_ih, const float* __restrict__ w_out,
        const f16* __restrict__ tT, f16* __restrict__ nhh,
        float* __restrict__ out, const float* __restrict__ partP,
        float* __restrict__ partC, int step_t) {
    constexpr int TILE_E = 10240;  // f16/buffer: A 128x32=4096 + B 192x32=6144
    __shared__ __align__(16) f16 lds[4 * TILE_E];  // 80 KB
    const int tid = threadIdx.x;
    const int lane = tid & 63, wave = tid >> 6;
    const int wm = wave >> 1, wn = wave & 1;
    // XCD-aware: id%8 = XCD; per XCD an 8bx x 8by patch (A dup x2, B dup x4).
    const int id = blockIdx.x;
    const int xcd = id & 7, slot = id >> 3;  // slot 0..63
    const int bx = (xcd & 1) * 8 + (slot & 7);
    const int by = (xcd >> 1) * 8 + (slot >> 3);
    const int b0 = by * 128, j0 = bx * 64;
    const int lrow = lane & 15, quad = lane >> 4;

    // ---- reduce previous step's delta partials (1/16 per block) ----
    // Plain loads BEFORE any gl_lds: these older vmem ops retire first, so
    // the counted vmcnt waits below remain (conservatively) correct.
    if (step_t > 0 && tid < 16) {
        const int b = b0 + bx * 8 + (tid >> 1), cc = tid & 1;
        float s = 0.f;
#pragma unroll
        for (int x = 0; x < 16; ++x) s += partP[x * 8192 + b * 2 + cc];
        out[b * (T_SZ * 2) + (step_t - 1) * 2 + cc] = s;
    }

    // ---- staging sources (all 4 waves; 5 gl_lds per thread per tile) ----
    const f16* ga[2];
    const f16* gb;
    {
        const int r = tid >> 2;  // 0..63
        const int cs = ((tid & 3) ^ ((tid >> 3) & 3)) * 8;  // inverse swizzle
#pragma unroll
        for (int i = 0; i < 2; ++i)
            ga[i] = hh + (size_t)(b0 + i * 64 + r) * H_SZ + cs;
        gb = wpk + (size_t)bx * (32 * 6144);
    }
    auto issueT = [&](int kt) {
        const int sb = (kt & 3) * TILE_E;
#pragma unroll
        for (int i = 0; i < 2; ++i)
            gl_lds16(ga[i] + kt * 32, &lds[sb + i * 2048 + tid * 8]);
#pragma unroll
        for (int i = 0; i < 3; ++i)
            gl_lds16(gb + kt * 6144 + i * 2048 + tid * 8,
                     &lds[sb + 4096 + i * 2048 + tid * 8]);
    };

    // ---- fragment read offsets (swizzled; 2-way bank aliasing = free) ----
    const int swz = (quad ^ ((lrow >> 1) & 3)) * 8;
    int offA[4], offB[6];
#pragma unroll
    for (int mi = 0; mi < 4; ++mi)
        offA[mi] = (wm * 64 + mi * 16 + lrow) * 32 + swz;
#pragma unroll
    for (int f = 0; f < 6; ++f)
        offB[f] = 4096 + ((f >> 1) * 64 + wn * 32 + (f & 1) * 16 + lrow) * 32 + swz;

    f32x4 acc[3][4][2] = {};

    // ---- prologue: 3 tiles in flight ----
    issueT(0);
    issueT(1);
    issueT(2);

    for (int tt = 0; tt < 32; ++tt) {
        // certify tile tt (5 loads); keep later tiles in flight
        if (tt < 30)       asm volatile("s_waitcnt vmcnt(10)" ::: "memory");
        else if (tt == 30) asm volatile("s_waitcnt vmcnt(5)" ::: "memory");
        else               asm volatile("s_waitcnt vmcnt(0)" ::: "memory");
        __builtin_amdgcn_s_barrier();
        asm volatile("" ::: "memory");
        const int rb = (tt & 3) * TILE_E;
        f16x8 aa[4], bv[6];
#pragma unroll
        for (int mi = 0; mi < 4; ++mi)
            aa[mi] = *(const f16x8*)&lds[rb + offA[mi]];
#pragma unroll
        for (int f = 0; f < 6; ++f)
            bv[f] = *(const f16x8*)&lds[rb + offB[f]];
        if (tt < 29) issueT(tt + 3);  // buffer (tt+3)&3 == (tt-1)&3: safe
        LGKM0();
        __builtin_amdgcn_s_setprio(1);
#pragma unroll
        for (int f = 0; f < 6; ++f) {
            const int g = f >> 1, ni = f & 1;
#pragma unroll
            for (int mi = 0; mi < 4; ++mi)
                acc[g][mi][ni] = __builtin_amdgcn_mfma_f32_16x16x32_f16(
                    aa[mi], bv[f], acc[g][mi][ni], 0, 0, 0);
        }
        __builtin_amdgcn_s_setprio(0);
    }

    // -------- fused epilogue: gates, h_next, delta partials --------
    float p0[4][4], p1[4][4];
#pragma unroll
    for (int mi = 0; mi < 4; ++mi)
#pragma unroll
        for (int reg = 0; reg < 4; ++reg) {
            const int b = b0 + wm * 64 + mi * 16 + quad * 4 + reg;
            if (step_t > 0) {
                f16x2 tv = *(const f16x2*)&tT[((size_t)(step_t - 1) * B_SZ + b) * 2];
                p0[mi][reg] = (float)tv[0];
                p1[mi][reg] = (float)tv[1];
            } else {
                p0[mi][reg] = 0.f;
                p1[mi][reg] = 0.f;
            }
        }

    float s0[4][4] = {}, s1[4][4] = {};
#pragma unroll
    for (int ni = 0; ni < 2; ++ni) {
        const int j = j0 + wn * 32 + ni * 16 + lrow;
        const float wr0 = w_ih[(0 * H_SZ + j) * 2 + 0];
        const float wr1 = w_ih[(0 * H_SZ + j) * 2 + 1];
        const float wz0 = w_ih[(1 * H_SZ + j) * 2 + 0];
        const float wz1 = w_ih[(1 * H_SZ + j) * 2 + 1];
        const float wn0 = w_ih[(2 * H_SZ + j) * 2 + 0];
        const float wn1 = w_ih[(2 * H_SZ + j) * 2 + 1];
        const float br = b_ih[0 * H_SZ + j] + b_hh[0 * H_SZ + j];
        const float bz = b_ih[1 * H_SZ + j] + b_hh[1 * H_SZ + j];
        const float bn = b_ih[2 * H_SZ + j];
        const float hbn = b_hh[2 * H_SZ + j];
        const float wo0 = w_out[j], wo1 = w_out[H_SZ + j];
#pragma unroll
        for (int mi = 0; mi < 4; ++mi) {
#pragma unroll
            for (int reg = 0; reg < 4; ++reg) {
                const int b = b0 + wm * 64 + mi * 16 + quad * 4 + reg;
                const float hr = acc[0][mi][ni][reg];
                const float hz = acc[1][mi][ni][reg];
                const float hn_ = acc[2][mi][ni][reg] + hbn;
                const float xr = wr0 * p0[mi][reg] + wr1 * p1[mi][reg] + br;
                const float xz = wz0 * p0[mi][reg] + wz1 * p1[mi][reg] + bz;
                const float xn = wn0 * p0[mi][reg] + wn1 * p1[mi][reg] + bn;
                const float r = fast_sigmoid(xr + hr);
                const float z = fast_sigmoid(xz + hz);
                const float n = fast_tanh(xn + r * hn_);
                const size_t idx = (size_t)b * H_SZ + j;
                const float hold = (float)hh[idx];
                const float hnew = (1.0f - z) * n + z * hold;
                nhh[idx] = (f16)hnew;
                s0[mi][reg] += hnew * wo0;
                s1[mi][reg] += hnew * wo1;
            }
        }
    }

    // per-wave lrow-reduction, then cross-wn merge via LDS, store partials
    float ra[4][4], rc[4][4];
#pragma unroll
    for (int mi = 0; mi < 4; ++mi)
#pragma unroll
        for (int reg = 0; reg < 4; ++reg) {
            float a = s0[mi][reg], c = s1[mi][reg];
#pragma unroll
            for (int m = 1; m < 16; m <<= 1) {
                a += __shfl_xor(a, m);
                c += __shfl_xor(c, m);
            }
            ra[mi][reg] = a;
            rc[mi][reg] = c;
        }
    float* red = (float*)lds;  // 1 KB scratch; K-loop LDS fully consumed
    __syncthreads();           // all waves done with LDS buffer reads
    if (wn == 1 && lrow == 0) {
#pragma unroll
        for (int mi = 0; mi < 4; ++mi)
#pragma unroll
            for (int reg = 0; reg < 4; ++reg) {
                const int key = wm * 64 + mi * 16 + quad * 4 + reg;
                red[key * 2 + 0] = ra[mi][reg];
                red[key * 2 + 1] = rc[mi][reg];
            }
    }
    __syncthreads();
    if (wn == 0 && lrow == 0) {
#pragma unroll
        for (int mi = 0; mi < 4; ++mi)
#pragma unroll
            for (int reg = 0; reg < 4; ++reg) {
                const int key = wm * 64 + mi * 16 + quad * 4 + reg;
                const int b = b0 + key;
                partC[bx * 8192 + b * 2 + 0] = ra[mi][reg] + red[key * 2 + 0];
                partC[bx * 8192 + b * 2 + 1] = rc[mi][reg] + red[key * 2 + 1];
            }
    }
}

// ---------------------------------------------------------------------------
// pred_deltas += b_out (t<49 already reduced into out); t=49 reduced here
// from the last partial buffer; pred_pos = cumsum.
__global__ __launch_bounds__(256) void final_kernel(
        float* __restrict__ out, float* __restrict__ pos,
        const float* __restrict__ b_out, const float* __restrict__ partLast) {
    int idx = blockIdx.x * 256 + threadIdx.x;  // b*2 + c
    if (idx >= B_SZ * 2) return;
    int b = idx >> 1, c = idx & 1;
    float bc = b_out[c];
    float acc = 0.0f;
    for (int t = 0; t < T_SZ - 1; ++t) {
        float d = out[b * (T_SZ * 2) + t * 2 + c] + bc;
        out[b * (T_SZ * 2) + t * 2 + c] = d;
        acc += d;
        pos[b * (T_SZ * 2) + t * 2 + c] = acc;
    }
    float s = 0.f;
#pragma unroll
    for (int x = 0; x < 16; ++x) s += partLast[x * 8192 + b * 2 + c];
    float d = s + bc;
    out[b * (T_SZ * 2) + (T_SZ - 1) * 2 + c] = d;
    acc += d;
    pos[b * (T_SZ * 2) + (T_SZ - 1) * 2 + c] = acc;
}

// ---------------------------------------------------------------------------
extern "C" void kernel_launch(void* const* d_in, const int* in_sizes, int n_in,
                              void* d_out, int out_size, void* d_ws, size_t ws_size,
                              hipStream_t stream) {
    const float* ev     = (const float*)d_in[0];
    const float* teach  = (const float*)d_in[1];
    const float* w_init = (const float*)d_in[2];
    const float* b_init = (const float*)d_in[3];
    const float* w_ih   = (const float*)d_in[4];
    const float* w_hh   = (const float*)d_in[5];
    const float* b_ih   = (const float*)d_in[6];
    const float* b_hh   = (const float*)d_in[7];
    const float* w_out  = (const float*)d_in[8];
    const float* b_out  = (const float*)d_in[9];

    float* out = (float*)d_out;                  // pred_deltas (B,T,2)
    float* pos = out + (size_t)B_SZ * T_SZ * 2;  // pred_pos    (B,T,2)

    // ws layout (f16 units): hA (4M), hB (4M), wpk (3M), winit (1M) = 24 MB.
    // ev_f16 aliases hB. After h0, winit region is dead and reused for:
    //   tT (f16, 409600 elems) @ winit+0
    //   pA (f32, 131072) @ winit+417792 (f16 units), pB after it.
    f16* ws = (f16*)d_ws;
    f16* hA    = ws;
    f16* hB    = hA + (size_t)B_SZ * H_SZ;
    f16* wpk   = hB + (size_t)B_SZ * H_SZ;
    f16* winit = wpk + (size_t)3 * H_SZ * H_SZ;
    f16* evf   = hB;  // alias
    f16* tT    = winit;
    float* pA  = (float*)(winit + 417792);
    float* pB  = pA + 131072;

    conv_kernel<<<(H_SZ * D_SZ) / 1024, 256, 0, stream>>>(w_init, winit, H_SZ * D_SZ);
    conv_kernel<<<(B_SZ * D_SZ) / 1024, 256, 0, stream>>>(ev, evf, B_SZ * D_SZ);
    prepack_kernel<<<dim3(3, 32, 16), 256, 0, stream>>>(w_hh, wpk);

    dim3 g0(H_SZ / 64, B_SZ / 128);  // (16, 32)
    h0_kernel<<<g0, 256, 0, stream>>>(evf, winit, b_init, hA);

    // winit consumed; build tT in its place
    ttrans_kernel<<<(T_SZ * B_SZ + 255) / 256, 256, 0, stream>>>(teach, tT);

    f16 *hc = hA, *hn = hB;
    for (int t = 0; t < T_SZ; ++t) {
        float* partC = (t & 1) ? pB : pA;
        float* partP = (t & 1) ? pA : pB;
        step_kernel<<<512, 256, 0, stream>>>(hc, wpk, b_hh, w_ih, b_ih, w_out,
                                             tT, hn, out, partP, partC, t);
        f16* tmp = hc; hc = hn; hn = tmp;
    }
    // t=49 is odd -> its partials are in pB
    final_kernel<<<(B_SZ * 2 + 255) / 256, 256, 0, stream>>>(out, pos, b_out, pB);
}